// Round 1
// baseline (249.529 us; speedup 1.0000x reference)
//
#include <hip/hip_runtime.h>
#include <hip/hip_bf16.h>
#include <math.h>

typedef __attribute__((ext_vector_type(8))) short short8;
typedef __attribute__((ext_vector_type(4))) float f32x4;

#define NB 32
#define ND 512
#define NC 512
#define NROW (NB*NC)   // 16384

__device__ __forceinline__ float bf2f(short u){
  union { float f; unsigned int i; } w; w.i = ((unsigned int)(unsigned short)u) << 16; return w.f;
}
__device__ __forceinline__ short f2bf(float f){
  union { float f; unsigned int i; } w; w.f = f;
  unsigned int x = w.i;
  return (short)((x + 0x7fffu + ((x >> 16) & 1u)) >> 16);  // RNE
}

// ---------------- input transpose: X[(b*C+c)][d] = residual[b][d][c], fp32 + bf16 ----------------
__global__ __launch_bounds__(256)
void transpose_in_k(const float* __restrict__ res, short* __restrict__ Xb, float* __restrict__ Xf)
{
  __shared__ float t[64][65];
  const int b = blockIdx.z;
  const int d0 = blockIdx.x * 64;
  const int c0 = blockIdx.y * 64;
  const int tid = threadIdx.x;
  const int j = tid & 63, i0 = tid >> 6;
  const float* src = res + (size_t)b * ND * NC;
#pragma unroll
  for (int p = 0; p < 16; p++){
    int i = p*4 + i0;
    t[i][j] = src[(size_t)(d0 + i) * NC + c0 + j];
  }
  __syncthreads();
#pragma unroll
  for (int p = 0; p < 16; p++){
    int i = p*4 + i0;                 // local c index
    float v = t[j][i];                // residual[b][d0+j][c0+i]
    size_t idx = ((size_t)(b * NC + c0 + i)) * ND + d0 + j;
    Xf[idx] = v;
    Xb[idx] = f2bf(v);
  }
}

// ---------------- 512x512 transpose+cast: Wt[c][r] = W[r][c] (bf16) ----------------
__global__ __launch_bounds__(256)
void transpose_cast_k(const float* __restrict__ W, short* __restrict__ Wt)
{
  __shared__ float t[64][65];
  const int r0 = blockIdx.x * 64;
  const int c0 = blockIdx.y * 64;
  const int tid = threadIdx.x;
  const int j = tid & 63, i0 = tid >> 6;
#pragma unroll
  for (int p = 0; p < 16; p++){
    int i = p*4 + i0;
    t[i][j] = W[(size_t)(r0 + i) * 512 + c0 + j];
  }
  __syncthreads();
#pragma unroll
  for (int p = 0; p < 16; p++){
    int i = p*4 + i0;
    Wt[(size_t)(c0 + i) * 512 + r0 + j] = f2bf(t[j][i]);
  }
}

// ---------------- straight cast fp32 -> bf16 (8 elems/thread) ----------------
__global__ __launch_bounds__(256)
void cast_bf_k(const float* __restrict__ src, short* __restrict__ dst)
{
  size_t i = ((size_t)blockIdx.x * 256 + threadIdx.x) * 8;
  f32x4 a = *reinterpret_cast<const f32x4*>(&src[i]);
  f32x4 b = *reinterpret_cast<const f32x4*>(&src[i + 4]);
  short8 o;
#pragma unroll
  for (int k = 0; k < 4; k++) o[k] = f2bf(a[k]);
#pragma unroll
  for (int k = 0; k < 4; k++) o[4 + k] = f2bf(b[k]);
  *reinterpret_cast<short8*>(&dst[i]) = o;
}

// ---------------- tiny bias precomputes ----------------
// t2[t] = sum_e bq[e]*wk[e][t]
__global__ void make_t2_k(const float* __restrict__ bq, const float* __restrict__ wk, float* __restrict__ t2)
{
  int t = blockIdx.x * 256 + threadIdx.x;
  float s = 0.f;
  for (int e = 0; e < 512; e++) s += bq[e] * wk[(size_t)e * 512 + t];
  t2[t] = s;
}
// c0[e] = sum_d wo[e][d]*bv[d] + bo[e]
__global__ void make_c0_k(const float* __restrict__ wo, const float* __restrict__ bv,
                          const float* __restrict__ bo, float* __restrict__ c0)
{
  int e = blockIdx.x * 256 + threadIdx.x;
  float s = bo[e];
  for (int d = 0; d < 512; d++) s += wo[(size_t)e * 512 + d] * bv[d];
  c0[e] = s;
}

// ---------------- GEMM: C[m][n] = sum_k A[m][k]*Bt[n][k], bf16 in, fp32 accum ----------------
// EPI 0: +bias[col], store bf16           (Y = X@A_T^T + t2)
// EPI 1: +bias[col]+Xres, store f32, BN-stat atomics   (H)
// EPI 2: +bias[col], exact gelu, store bf16            (G)
// EPI 3: +bias[col]+bf16 HNb, store bf16               (y = f + hn)
// EPI 4: store bf16 plain                              (A_T, M precompute)
template<int EPI>
__global__ __launch_bounds__(256, 2)
void gemm_k(const short* __restrict__ A, const short* __restrict__ Bt,
            int M, int N, int K,
            const float* __restrict__ bias,
            const float* __restrict__ Xres,
            float* __restrict__ Cf,
            short* __restrict__ Cb,
            const short* __restrict__ HNb,
            float* __restrict__ bnsum, float* __restrict__ bnsumsq)
{
  __shared__ short As[128 * 64];
  __shared__ short Bs[128 * 64];
  const int tid = threadIdx.x;
  const int lane = tid & 63;
  const int wave = tid >> 6;
  const int bm = blockIdx.x * 128;
  const int bn = blockIdx.y * 128;
  const int wm = (wave >> 1) * 64;
  const int wn = (wave & 1) * 64;

  f32x4 acc[4][4];
#pragma unroll
  for (int i = 0; i < 4; i++)
#pragma unroll
    for (int j = 0; j < 4; j++) acc[i][j] = (f32x4){0.f, 0.f, 0.f, 0.f};

  const int r0 = tid >> 3;   // staging row within 32-row group
  const int g0 = tid & 7;    // 16B granule

  for (int kt = 0; kt < K; kt += 64) {
    short8 ra[4], rb[4];
#pragma unroll
    for (int jj = 0; jj < 4; jj++){
      int row = jj * 32 + r0;
      ra[jj] = *reinterpret_cast<const short8*>(&A [(size_t)(bm + row) * K + kt + g0 * 8]);
      rb[jj] = *reinterpret_cast<const short8*>(&Bt[(size_t)(bn + row) * K + kt + g0 * 8]);
    }
    __syncthreads();
#pragma unroll
    for (int jj = 0; jj < 4; jj++){
      int row = jj * 32 + r0;
      int gs = (g0 ^ (row & 7)) * 8;   // XOR swizzle kills stride-128B bank conflicts (T2)
      *reinterpret_cast<short8*>(&As[row * 64 + gs]) = ra[jj];
      *reinterpret_cast<short8*>(&Bs[row * 64 + gs]) = rb[jj];
    }
    __syncthreads();
#pragma unroll
    for (int kk = 0; kk < 2; kk++){
      short8 af[4], bfr[4];
      int gl = kk * 4 + (lane >> 4);
#pragma unroll
      for (int i = 0; i < 4; i++){
        int row = wm + i * 16 + (lane & 15);
        af[i] = *reinterpret_cast<const short8*>(&As[row * 64 + ((gl ^ (row & 7)) * 8)]);
      }
#pragma unroll
      for (int j = 0; j < 4; j++){
        int row = wn + j * 16 + (lane & 15);
        bfr[j] = *reinterpret_cast<const short8*>(&Bs[row * 64 + ((gl ^ (row & 7)) * 8)]);
      }
#pragma unroll
      for (int i = 0; i < 4; i++)
#pragma unroll
        for (int j = 0; j < 4; j++)
          acc[i][j] = __builtin_amdgcn_mfma_f32_16x16x32_bf16(af[i], bfr[j], acc[i][j], 0, 0, 0);
    }
  }

  const int rb0 = bm + wm + ((lane >> 4) << 2);   // C/D: row=(lane>>4)*4+reg
  const int cb0 = bn + wn + (lane & 15);          // C/D: col=lane&15

  if (EPI == 1) {
#pragma unroll
    for (int i = 0; i < 4; i++){
#pragma unroll
      for (int r = 0; r < 4; r++){
        int row = rb0 + i * 16 + r;
        float s1 = 0.f, s2 = 0.f;
#pragma unroll
        for (int j = 0; j < 4; j++){
          int col = cb0 + j * 16;
          float v = acc[i][j][r] + bias[col] + Xres[(size_t)row * N + col];
          Cf[(size_t)row * N + col] = v;
          s1 += v; s2 += v * v;
        }
#pragma unroll
        for (int mm = 1; mm < 16; mm <<= 1){ s1 += __shfl_xor(s1, mm, 64); s2 += __shfl_xor(s2, mm, 64); }
        if ((lane & 15) == 0){
          atomicAdd(&bnsum  [row & (NC - 1)], s1);
          atomicAdd(&bnsumsq[row & (NC - 1)], s2);
        }
      }
    }
  } else {
#pragma unroll
    for (int i = 0; i < 4; i++){
#pragma unroll
      for (int j = 0; j < 4; j++){
        int col = cb0 + j * 16;
#pragma unroll
        for (int r = 0; r < 4; r++){
          int row = rb0 + i * 16 + r;
          float v = acc[i][j][r];
          if (EPI == 0) v += bias[col];
          else if (EPI == 2){ v += bias[col]; v = 0.5f * v * (1.0f + erff(v * 0.70710678118654752f)); }
          else if (EPI == 3){ v += bias[col] + bf2f(HNb[(size_t)row * N + col]); }
          Cb[(size_t)row * N + col] = f2bf(v);
        }
      }
    }
  }
}

// ---------------- correlation + softmax(8) + z; Z overwrites Y in place ----------------
__global__ __launch_bounds__(256)
void attn_k(const short* __restrict__ Xb, short* __restrict__ YZ)
{
  __shared__ short xsh[4][512];
  const int lane = threadIdx.x & 63;
  const int wave = threadIdx.x >> 6;
  for (int it = 0; it < 4; ++it) {
    int row = (it * (int)gridDim.x + (int)blockIdx.x) * 4 + wave;
    short8 xv = *reinterpret_cast<const short8*>(&Xb[(size_t)row * 512 + lane * 8]);
    short8 yv = *reinterpret_cast<const short8*>(&YZ[(size_t)row * 512 + lane * 8]);
    __syncthreads();
    *reinterpret_cast<short8*>(&xsh[wave][lane * 8]) = xv;
    __syncthreads();
    float y[8];
#pragma unroll
    for (int i = 0; i < 8; i++) y[i] = bf2f(yv[i]);
    float xs[8][8];
    float sc[8];
#pragma unroll
    for (int s = 0; s < 8; s++){
      int off = (lane * 8 + 64 * s) & 511;
      short8 xr = *reinterpret_cast<const short8*>(&xsh[wave][off]);
      float p = 0.f;
#pragma unroll
      for (int i = 0; i < 8; i++){ float xf = bf2f(xr[i]); xs[s][i] = xf; p += y[i] * xf; }
#pragma unroll
      for (int mm = 1; mm < 64; mm <<= 1) p += __shfl_xor(p, mm, 64);
      sc[s] = p * 0.044194173824159216f;   // 512^-0.5
    }
    float mx = sc[0];
#pragma unroll
    for (int s = 1; s < 8; s++) mx = fmaxf(mx, sc[s]);
    float es[8], sum = 0.f;
#pragma unroll
    for (int s = 0; s < 8; s++){ es[s] = __expf(sc[s] - mx); sum += es[s]; }
    float inv = 1.0f / sum;
    float z[8] = {0.f,0.f,0.f,0.f,0.f,0.f,0.f,0.f};
#pragma unroll
    for (int s = 0; s < 8; s++){
      float a = es[s] * inv;
#pragma unroll
      for (int i = 0; i < 8; i++) z[i] += a * xs[s][i];
    }
    short8 zv;
#pragma unroll
    for (int i = 0; i < 8; i++) zv[i] = f2bf(z[i]);
    *reinterpret_cast<short8*>(&YZ[(size_t)row * 512 + lane * 8]) = zv;
  }
}

// ---------------- BN finalize ----------------
__global__ void bn_finalize_k(const float* __restrict__ bnsum, const float* __restrict__ bnsumsq,
                              const float* __restrict__ bn_w, float* __restrict__ mu, float* __restrict__ scv)
{
  int c = blockIdx.x * 256 + threadIdx.x;
  float m = bnsum[c] * (1.0f / 16384.0f);
  float var = bnsumsq[c] * (1.0f / 16384.0f) - m * m;
  float rs = rsqrtf(var + 1e-5f);
  mu[c] = m;
  scv[c] = rs * bn_w[c];
}

// ---------------- hn = (h - mu[c])*scv[c] + bn_b[c]  -> bf16 ----------------
__global__ __launch_bounds__(256)
void make_hn_k(const float* __restrict__ H, const float* __restrict__ mu,
               const float* __restrict__ scv, const float* __restrict__ bnb,
               short* __restrict__ HNb)
{
  size_t i = ((size_t)blockIdx.x * 256 + threadIdx.x) * 8;
  int row = (int)(i >> 9);
  int c = row & (NC - 1);
  float m = mu[c], sc = scv[c], bb = bnb[c];
  f32x4 a = *reinterpret_cast<const f32x4*>(&H[i]);
  f32x4 b = *reinterpret_cast<const f32x4*>(&H[i + 4]);
  short8 o;
#pragma unroll
  for (int k = 0; k < 4; k++) o[k]     = f2bf((a[k] - m) * sc + bb);
#pragma unroll
  for (int k = 0; k < 4; k++) o[4 + k] = f2bf((b[k] - m) * sc + bb);
  *reinterpret_cast<short8*>(&HNb[i]) = o;
}

// ---------------- LayerNorm(512) + transposed output write ----------------
__global__ __launch_bounds__(256)
void ln_transpose_k(const short* __restrict__ Yb, const float* __restrict__ lnw,
                    const float* __restrict__ lnb, float* __restrict__ out)
{
  __shared__ short yn[64][520];
  const int tid = threadIdx.x;
  const int lane = tid & 63;
  const int wave = tid >> 6;
  const int b = blockIdx.x >> 3;
  const int c0 = (blockIdx.x & 7) * 64;
  float w8[8], bb8[8];
#pragma unroll
  for (int i = 0; i < 8; i++){ w8[i] = lnw[lane * 8 + i]; bb8[i] = lnb[lane * 8 + i]; }
  for (int rr = 0; rr < 16; rr++){
    int cl = wave * 16 + rr;
    int row = b * NC + c0 + cl;
    short8 yv = *reinterpret_cast<const short8*>(&Yb[(size_t)row * 512 + lane * 8]);
    float v[8]; float s = 0.f, s2 = 0.f;
#pragma unroll
    for (int i = 0; i < 8; i++){ v[i] = bf2f(yv[i]); s += v[i]; s2 += v[i] * v[i]; }
#pragma unroll
    for (int mm = 1; mm < 64; mm <<= 1){ s += __shfl_xor(s, mm, 64); s2 += __shfl_xor(s2, mm, 64); }
    float mean = s * (1.f / 512.f);
    float var = s2 * (1.f / 512.f) - mean * mean;
    float rs = rsqrtf(var + 1e-5f);
    short8 o;
#pragma unroll
    for (int i = 0; i < 8; i++) o[i] = f2bf((v[i] - mean) * rs * w8[i] + bb8[i]);
    *reinterpret_cast<short8*>(&yn[cl][lane * 8]) = o;
  }
  __syncthreads();
  size_t ob = (size_t)b * (ND * NC);
#pragma unroll 4
  for (int itx = 0; itx < 128; itx++){
    int idx = itx * 256 + tid;
    int d = idx >> 6;
    int cl = idx & 63;
    out[ob + (size_t)d * NC + c0 + cl] = bf2f(yn[cl][d]);
  }
}

extern "C" void kernel_launch(void* const* d_in, const int* in_sizes, int n_in,
                              void* d_out, int out_size, void* d_ws, size_t ws_size,
                              hipStream_t stream)
{
  const float* residual = (const float*)d_in[0];
  const float* wq   = (const float*)d_in[1];
  const float* bq   = (const float*)d_in[2];
  const float* wk   = (const float*)d_in[3];
  const float* wv   = (const float*)d_in[5];
  const float* bv   = (const float*)d_in[6];
  const float* wo   = (const float*)d_in[7];
  const float* bo   = (const float*)d_in[8];
  const float* bn_w = (const float*)d_in[9];
  const float* bn_b = (const float*)d_in[10];
  const float* w1   = (const float*)d_in[11];
  const float* b1   = (const float*)d_in[12];
  const float* w2   = (const float*)d_in[13];
  const float* b2   = (const float*)d_in[14];
  const float* ln_w = (const float*)d_in[15];
  const float* ln_b = (const float*)d_in[16];

  char* ws = (char*)d_ws;
  short* Xb  = (short*)(ws);                        // 16 MB bf16 X[row][d]
  float* Xf  = (float*)(ws + ((size_t)16 << 20));   // 32 MB f32 X[row][d]
  short* YZ  = (short*)(ws + ((size_t)48 << 20));   // 16 MB Y -> Z -> y
  short* HNb = (short*)(ws + ((size_t)64 << 20));   // 16 MB hn bf16
  char*  wsw = ws + ((size_t)80 << 20);
  short* wkT = (short*)(wsw);
  short* wqT = (short*)(wsw + ((size_t)512 << 10));
  short* wvT = (short*)(wsw + ((size_t)1024 << 10));
  short* woB = (short*)(wsw + ((size_t)1536 << 10));
  short* w1B = (short*)(wsw + ((size_t)2048 << 10));
  short* w2B = (short*)(wsw + ((size_t)3072 << 10));
  short* AT  = (short*)(wsw + ((size_t)4096 << 10));
  short* MB  = (short*)(wsw + ((size_t)4608 << 10));
  float* t2  = (float*)(wsw + ((size_t)5120 << 10));
  float* c0v = (float*)(wsw + ((size_t)5120 << 10) + 2048);
  float* bnsum   = (float*)(wsw + ((size_t)5120 << 10) + 4096);
  float* bnsumsq = (float*)(wsw + ((size_t)5120 << 10) + 6144);
  float* muv = (float*)(wsw + ((size_t)5120 << 10) + 8192);
  float* scv = (float*)(wsw + ((size_t)5120 << 10) + 10240);

  float* Hf = (float*)d_out;          // H lives in d_out until consumed
  short* Gb = (short*)d_out;          // then G (bf16 16384x1024 = 32MB) reuses it

  hipMemsetAsync(bnsum, 0, 4096, stream);

  transpose_in_k<<<dim3(8, 8, 32), 256, 0, stream>>>(residual, Xb, Xf);
  transpose_cast_k<<<dim3(8, 8), 256, 0, stream>>>(wk, wkT);
  transpose_cast_k<<<dim3(8, 8), 256, 0, stream>>>(wq, wqT);
  transpose_cast_k<<<dim3(8, 8), 256, 0, stream>>>(wv, wvT);
  cast_bf_k<<<128, 256, 0, stream>>>(wo, woB);
  cast_bf_k<<<256, 256, 0, stream>>>(w1, w1B);
  cast_bf_k<<<256, 256, 0, stream>>>(w2, w2B);
  make_t2_k<<<2, 256, 0, stream>>>(bq, wk, t2);
  make_c0_k<<<2, 256, 0, stream>>>(wo, bv, bo, c0v);

  // A_T[t][d] = sum_e wk[e][t]*wq[e][d];  M[e][t] = sum_d wo[e][d]*wv[d][t]
  gemm_k<4><<<dim3(4, 4), 256, 0, stream>>>(wkT, wqT, 512, 512, 512, nullptr, nullptr, nullptr, AT, nullptr, nullptr, nullptr);
  gemm_k<4><<<dim3(4, 4), 256, 0, stream>>>(woB, wvT, 512, 512, 512, nullptr, nullptr, nullptr, MB, nullptr, nullptr, nullptr);

  // Y = X @ A_T^T + t2
  gemm_k<0><<<dim3(128, 4), 256, 0, stream>>>(Xb, AT, NROW, 512, 512, t2, nullptr, nullptr, YZ, nullptr, nullptr, nullptr);
  // scores/softmax/z (in place Y->Z)
  attn_k<<<1024, 256, 0, stream>>>(Xb, YZ);
  // H = Z @ M^T + c0 + X ; BN stats
  gemm_k<1><<<dim3(128, 4), 256, 0, stream>>>(YZ, MB, NROW, 512, 512, c0v, Xf, Hf, nullptr, nullptr, bnsum, bnsumsq);
  bn_finalize_k<<<2, 256, 0, stream>>>(bnsum, bnsumsq, bn_w, muv, scv);
  make_hn_k<<<4096, 256, 0, stream>>>(Hf, muv, scv, bn_b, HNb);
  // G = gelu(HN @ W1^T + b1)   (G overwrites d_out)
  gemm_k<2><<<dim3(128, 8), 256, 0, stream>>>(HNb, w1B, NROW, 1024, 512, b1, nullptr, nullptr, Gb, nullptr, nullptr, nullptr);
  // y = G @ W2^T + b2 + HN
  gemm_k<3><<<dim3(128, 4), 256, 0, stream>>>(Gb, w2B, NROW, 512, 1024, b2, nullptr, nullptr, YZ, HNb, nullptr, nullptr);
  // LayerNorm + transposed output
  ln_transpose_k<<<256, 256, 0, stream>>>(YZ, ln_w, ln_b, (float*)d_out);
}

// Round 2
// 220.739 us; speedup vs baseline: 1.1304x; 1.1304x over previous
//
#include <hip/hip_runtime.h>
#include <hip/hip_bf16.h>
#include <math.h>

typedef __attribute__((ext_vector_type(8))) short short8;
typedef __attribute__((ext_vector_type(4))) float f32x4;

#define NB 32
#define ND 512
#define NC 512
#define NROW (NB*NC)   // 16384

__device__ __forceinline__ float bf2f(short u){
  union { float f; unsigned int i; } w; w.i = ((unsigned int)(unsigned short)u) << 16; return w.f;
}
__device__ __forceinline__ short f2bf(float f){
  union { float f; unsigned int i; } w; w.f = f;
  unsigned int x = w.i;
  return (short)((x + 0x7fffu + ((x >> 16) & 1u)) >> 16);  // RNE
}

// async global->LDS, 16B per lane; LDS dest = wave-uniform base + lane*16
__device__ __forceinline__ void gload16(const short* g, short* l){
  __builtin_amdgcn_global_load_lds(
      (const __attribute__((address_space(1))) unsigned int*)(uintptr_t)g,
      (__attribute__((address_space(3))) unsigned int*)(unsigned int)(uintptr_t)l,
      16, 0, 0);
}

// ---------------- input transpose: Xb[(b*C+c)][d] = residual[b][d][c] (bf16) ----------------
__global__ __launch_bounds__(256)
void transpose_in_k(const float* __restrict__ res, short* __restrict__ Xb)
{
  __shared__ float t[64][65];
  const int b = blockIdx.z;
  const int d0 = blockIdx.x * 64;
  const int c0 = blockIdx.y * 64;
  const int tid = threadIdx.x;
  const int j = tid & 63, i0 = tid >> 6;
  const float* src = res + (size_t)b * ND * NC;
#pragma unroll
  for (int p = 0; p < 16; p++){
    int i = p*4 + i0;
    t[i][j] = src[(size_t)(d0 + i) * NC + c0 + j];
  }
  __syncthreads();
#pragma unroll
  for (int p = 0; p < 16; p++){
    int i = p*4 + i0;
    Xb[((size_t)(b * NC + c0 + i)) * ND + d0 + j] = f2bf(t[j][i]);
  }
}

// ---------------- 3x 512x512 transpose+cast via blockIdx.z ----------------
__global__ __launch_bounds__(256)
void tcast3_k(const float* __restrict__ wk, const float* __restrict__ wq, const float* __restrict__ wv,
              short* __restrict__ wkT, short* __restrict__ wqT, short* __restrict__ wvT)
{
  const float* W = (blockIdx.z == 0) ? wk : (blockIdx.z == 1) ? wq : wv;
  short* Wt      = (blockIdx.z == 0) ? wkT : (blockIdx.z == 1) ? wqT : wvT;
  __shared__ float t[64][65];
  const int r0 = blockIdx.x * 64;
  const int c0 = blockIdx.y * 64;
  const int tid = threadIdx.x;
  const int j = tid & 63, i0 = tid >> 6;
#pragma unroll
  for (int p = 0; p < 16; p++){
    int i = p*4 + i0;
    t[i][j] = W[(size_t)(r0 + i) * 512 + c0 + j];
  }
  __syncthreads();
#pragma unroll
  for (int p = 0; p < 16; p++){
    int i = p*4 + i0;
    Wt[(size_t)(c0 + i) * 512 + r0 + j] = f2bf(t[j][i]);
  }
}

// ---------------- 3x cast fp32->bf16 in one launch ----------------
__global__ __launch_bounds__(256)
void cast3_k(const float* __restrict__ wo, const float* __restrict__ w1, const float* __restrict__ w2,
             short* __restrict__ woB, short* __restrict__ w1B, short* __restrict__ w2B)
{
  int blk = blockIdx.x;
  const float* src; short* dst; int base;
  if (blk < 128){ src = wo; dst = woB; base = blk; }
  else if (blk < 384){ src = w1; dst = w1B; base = blk - 128; }
  else { src = w2; dst = w2B; base = blk - 384; }
  size_t i = ((size_t)base * 256 + threadIdx.x) * 8;
  f32x4 a = *reinterpret_cast<const f32x4*>(&src[i]);
  f32x4 b = *reinterpret_cast<const f32x4*>(&src[i + 4]);
  short8 o;
#pragma unroll
  for (int k = 0; k < 4; k++) o[k] = f2bf(a[k]);
#pragma unroll
  for (int k = 0; k < 4; k++) o[4 + k] = f2bf(b[k]);
  *reinterpret_cast<short8*>(&dst[i]) = o;
}

// ---------------- t2 and c0 bias precomputes in one launch ----------------
__global__ void t2c0_k(const float* __restrict__ bq, const float* __restrict__ wk,
                       const float* __restrict__ wo, const float* __restrict__ bv,
                       const float* __restrict__ bo, float* __restrict__ t2, float* __restrict__ c0)
{
  int idx = blockIdx.x * 256 + threadIdx.x;
  if (blockIdx.y == 0){
    float s = 0.f;
    for (int e = 0; e < 512; e++) s += bq[e] * wk[(size_t)e * 512 + idx];
    t2[idx] = s;
  } else {
    float s = bo[idx];
    for (int d = 0; d < 512; d++) s += wo[(size_t)idx * 512 + d] * bv[d];
    c0[idx] = s;
  }
}

// ---------------- GEMM: C[m][n] = sum_k A[m][k]*Bt[n][k], bf16 in, fp32 accum ----------------
// m97 structure: global_load_lds(16B) direct staging, pre-swizzled global source,
// linear LDS dest, 2-barrier K-loop, swizzled ds_read_b128.
// EPI 0: +bias[col] -> bf16                 (Y)
// EPI 1: +bias[col]+bf16 Xres -> bf16, BN-stat atomics (H)
// EPI 2: +bias[col], exact gelu -> bf16     (G)
// EPI 3: +bias[col]+bf16 HNb -> bf16        (y)
// EPI 4: plain -> bf16; grid.z selects (A,Bt,Cb) or (A2,Bt2,Cb2)  (A_T, M)
template<int EPI>
__global__ __launch_bounds__(256)
void gemm_k(const short* __restrict__ A, const short* __restrict__ Bt,
            const short* __restrict__ A2, const short* __restrict__ Bt2,
            int M, int N, int K,
            const float* __restrict__ bias,
            const short* __restrict__ Xres,
            short* __restrict__ Cb, short* __restrict__ Cb2,
            const short* __restrict__ HNb,
            float* __restrict__ bnsum, float* __restrict__ bnsumsq)
{
  if (EPI == 4 && blockIdx.z == 1){ A = A2; Bt = Bt2; Cb = Cb2; }
  __shared__ short As[128 * 64];
  __shared__ short Bs[128 * 64];
  const int tid = threadIdx.x;
  const int lane = tid & 63;
  const int wave = tid >> 6;
  const int bm = blockIdx.x * 128;
  const int bn = blockIdx.y * 128;
  const int wm = (wave >> 1) * 64;
  const int wn = (wave & 1) * 64;

  f32x4 acc[4][4];
#pragma unroll
  for (int i = 0; i < 4; i++)
#pragma unroll
    for (int j = 0; j < 4; j++) acc[i][j] = (f32x4){0.f, 0.f, 0.f, 0.f};

  // staging: wave w covers rows [w*32, w*32+32). Per gload: 8 rows x 128B.
  // LDS is written linearly (base + lane*16); the SOURCE column granule is
  // pre-swizzled by row&7 so swizzled ds_reads come out conflict-free.
  const int srow = lane >> 3;                      // row within 8-row group (= row&7)
  const int gcol = ((lane & 7) ^ srow) * 8;        // pre-swizzled K-granule (shorts)
  const short* aptr = A  + (size_t)(bm + wave * 32 + srow) * K + gcol;
  const short* bptr = Bt + (size_t)(bn + wave * 32 + srow) * K + gcol;
  short* asl = &As[wave * 32 * 64];
  short* bsl = &Bs[wave * 32 * 64];

  for (int kt = 0; kt < K; kt += 64) {
#pragma unroll
    for (int q = 0; q < 4; q++){
      gload16(aptr + (size_t)(q * 8) * K + kt, asl + q * 512);
      gload16(bptr + (size_t)(q * 8) * K + kt, bsl + q * 512);
    }
    asm volatile("s_waitcnt vmcnt(0)" ::: "memory");
    __syncthreads();
#pragma unroll
    for (int kk = 0; kk < 2; kk++){
      short8 af[4], bfr[4];
      const int gl = kk * 4 + (lane >> 4);
      const int sw = (gl ^ (lane & 7)) * 8;        // read-side swizzle (row&7 == lane&7)
#pragma unroll
      for (int i = 0; i < 4; i++)
        af[i]  = *reinterpret_cast<const short8*>(&As[(wm + i * 16 + (lane & 15)) * 64 + sw]);
#pragma unroll
      for (int j = 0; j < 4; j++)
        bfr[j] = *reinterpret_cast<const short8*>(&Bs[(wn + j * 16 + (lane & 15)) * 64 + sw]);
#pragma unroll
      for (int i = 0; i < 4; i++)
#pragma unroll
        for (int j = 0; j < 4; j++)
          acc[i][j] = __builtin_amdgcn_mfma_f32_16x16x32_bf16(af[i], bfr[j], acc[i][j], 0, 0, 0);
    }
    __syncthreads();
  }

  const int rb0 = bm + wm + ((lane >> 4) << 2);   // C/D: row=(lane>>4)*4+reg
  const int cb0 = bn + wn + (lane & 15);          // C/D: col=lane&15

  if (EPI == 1) {
#pragma unroll
    for (int i = 0; i < 4; i++){
#pragma unroll
      for (int r = 0; r < 4; r++){
        int row = rb0 + i * 16 + r;
        float s1 = 0.f, s2 = 0.f;
#pragma unroll
        for (int j = 0; j < 4; j++){
          int col = cb0 + j * 16;
          float v = acc[i][j][r] + bias[col] + bf2f(Xres[(size_t)row * N + col]);
          Cb[(size_t)row * N + col] = f2bf(v);
          s1 += v; s2 += v * v;
        }
#pragma unroll
        for (int mm = 1; mm < 16; mm <<= 1){ s1 += __shfl_xor(s1, mm, 64); s2 += __shfl_xor(s2, mm, 64); }
        if ((lane & 15) == 0){
          atomicAdd(&bnsum  [row & (NC - 1)], s1);
          atomicAdd(&bnsumsq[row & (NC - 1)], s2);
        }
      }
    }
  } else {
#pragma unroll
    for (int i = 0; i < 4; i++){
#pragma unroll
      for (int j = 0; j < 4; j++){
        int col = cb0 + j * 16;
#pragma unroll
        for (int r = 0; r < 4; r++){
          int row = rb0 + i * 16 + r;
          float v = acc[i][j][r];
          if (EPI == 0) v += bias[col];
          else if (EPI == 2){ v += bias[col]; v = 0.5f * v * (1.0f + erff(v * 0.70710678118654752f)); }
          else if (EPI == 3){ v += bias[col] + bf2f(HNb[(size_t)row * N + col]); }
          Cb[(size_t)row * N + col] = f2bf(v);
        }
      }
    }
  }
}

// ---------------- correlation + softmax(8) + z; Z overwrites Y in place ----------------
__global__ __launch_bounds__(256)
void attn_k(const short* __restrict__ Xb, short* __restrict__ YZ)
{
  __shared__ short xsh[4][512];
  const int lane = threadIdx.x & 63;
  const int wave = threadIdx.x >> 6;
  for (int it = 0; it < 4; ++it) {
    int row = (it * (int)gridDim.x + (int)blockIdx.x) * 4 + wave;
    short8 xv = *reinterpret_cast<const short8*>(&Xb[(size_t)row * 512 + lane * 8]);
    short8 yv = *reinterpret_cast<const short8*>(&YZ[(size_t)row * 512 + lane * 8]);
    *reinterpret_cast<short8*>(&xsh[wave][lane * 8]) = xv;   // per-wave slice, no barrier needed
    float y[8];
#pragma unroll
    for (int i = 0; i < 8; i++) y[i] = bf2f(yv[i]);
    float xs[8][8];
    float sc[8];
#pragma unroll
    for (int s = 0; s < 8; s++){
      int off = (lane * 8 + 64 * s) & 511;
      short8 xr = *reinterpret_cast<const short8*>(&xsh[wave][off]);
      float p = 0.f;
#pragma unroll
      for (int i = 0; i < 8; i++){ float xf = bf2f(xr[i]); xs[s][i] = xf; p += y[i] * xf; }
#pragma unroll
      for (int mm = 1; mm < 64; mm <<= 1) p += __shfl_xor(p, mm, 64);
      sc[s] = p * 0.044194173824159216f;   // 512^-0.5
    }
    float mx = sc[0];
#pragma unroll
    for (int s = 1; s < 8; s++) mx = fmaxf(mx, sc[s]);
    float es[8], sum = 0.f;
#pragma unroll
    for (int s = 0; s < 8; s++){ es[s] = __expf(sc[s] - mx); sum += es[s]; }
    float inv = 1.0f / sum;
    float z[8] = {0.f,0.f,0.f,0.f,0.f,0.f,0.f,0.f};
#pragma unroll
    for (int s = 0; s < 8; s++){
      float a = es[s] * inv;
#pragma unroll
      for (int i = 0; i < 8; i++) z[i] += a * xs[s][i];
    }
    short8 zv;
#pragma unroll
    for (int i = 0; i < 8; i++) zv[i] = f2bf(z[i]);
    *reinterpret_cast<short8*>(&YZ[(size_t)row * 512 + lane * 8]) = zv;
  }
}

// ---------------- hn = (h - mu[c])*rsqrt(var+eps)*bnw[c] + bnb[c], finalize fused ----------------
__global__ __launch_bounds__(256)
void make_hn_k(const short* __restrict__ Hb, const float* __restrict__ bnsum,
               const float* __restrict__ bnsumsq, const float* __restrict__ bnw,
               const float* __restrict__ bnb, short* __restrict__ HNb)
{
  size_t i = ((size_t)blockIdx.x * 256 + threadIdx.x) * 8;
  int c = ((int)(i >> 9)) & (NC - 1);
  float m = bnsum[c] * (1.0f / 16384.0f);
  float var = bnsumsq[c] * (1.0f / 16384.0f) - m * m;
  float sc = rsqrtf(var + 1e-5f) * bnw[c];
  float bb = bnb[c];
  short8 h = *reinterpret_cast<const short8*>(&Hb[i]);
  short8 o;
#pragma unroll
  for (int k = 0; k < 8; k++) o[k] = f2bf((bf2f(h[k]) - m) * sc + bb);
  *reinterpret_cast<short8*>(&HNb[i]) = o;
}

// ---------------- LayerNorm(512) + transposed output write ----------------
__global__ __launch_bounds__(256)
void ln_transpose_k(const short* __restrict__ Yb, const float* __restrict__ lnw,
                    const float* __restrict__ lnb, float* __restrict__ out)
{
  __shared__ short yn[64][520];
  const int tid = threadIdx.x;
  const int lane = tid & 63;
  const int wave = tid >> 6;
  const int b = blockIdx.x >> 3;
  const int c0 = (blockIdx.x & 7) * 64;
  float w8[8], bb8[8];
#pragma unroll
  for (int i = 0; i < 8; i++){ w8[i] = lnw[lane * 8 + i]; bb8[i] = lnb[lane * 8 + i]; }
  for (int rr = 0; rr < 16; rr++){
    int cl = wave * 16 + rr;
    int row = b * NC + c0 + cl;
    short8 yv = *reinterpret_cast<const short8*>(&Yb[(size_t)row * 512 + lane * 8]);
    float v[8]; float s = 0.f, s2 = 0.f;
#pragma unroll
    for (int i = 0; i < 8; i++){ v[i] = bf2f(yv[i]); s += v[i]; s2 += v[i] * v[i]; }
#pragma unroll
    for (int mm = 1; mm < 64; mm <<= 1){ s += __shfl_xor(s, mm, 64); s2 += __shfl_xor(s2, mm, 64); }
    float mean = s * (1.f / 512.f);
    float var = s2 * (1.f / 512.f) - mean * mean;
    float rs = rsqrtf(var + 1e-5f);
    short8 o;
#pragma unroll
    for (int i = 0; i < 8; i++) o[i] = f2bf((v[i] - mean) * rs * w8[i] + bb8[i]);
    *reinterpret_cast<short8*>(&yn[cl][lane * 8]) = o;
  }
  __syncthreads();
  size_t ob = (size_t)b * (ND * NC);
#pragma unroll 4
  for (int itx = 0; itx < 128; itx++){
    int idx = itx * 256 + tid;
    int d = idx >> 6;
    int cl = idx & 63;
    out[ob + (size_t)d * NC + c0 + cl] = bf2f(yn[cl][d]);
  }
}

extern "C" void kernel_launch(void* const* d_in, const int* in_sizes, int n_in,
                              void* d_out, int out_size, void* d_ws, size_t ws_size,
                              hipStream_t stream)
{
  const float* residual = (const float*)d_in[0];
  const float* wq   = (const float*)d_in[1];
  const float* bq   = (const float*)d_in[2];
  const float* wk   = (const float*)d_in[3];
  const float* wv   = (const float*)d_in[5];
  const float* bv   = (const float*)d_in[6];
  const float* wo   = (const float*)d_in[7];
  const float* bo   = (const float*)d_in[8];
  const float* bn_w = (const float*)d_in[9];
  const float* bn_b = (const float*)d_in[10];
  const float* w1   = (const float*)d_in[11];
  const float* b1   = (const float*)d_in[12];
  const float* w2   = (const float*)d_in[13];
  const float* b2   = (const float*)d_in[14];
  const float* ln_w = (const float*)d_in[15];
  const float* ln_b = (const float*)d_in[16];

  char* ws = (char*)d_ws;
  short* Xb  = (short*)(ws);                        // 16 MiB  X bf16 [16384][512]
  short* YZ  = (short*)(ws + ((size_t)16 << 20));   // 16 MiB  Y -> Z -> y
  short* HNb = (short*)(ws + ((size_t)32 << 20));   // 16 MiB  hn bf16
  short* Hb  = (short*)(ws + ((size_t)48 << 20));   // 16 MiB  h bf16
  char*  wsw = ws + ((size_t)64 << 20);
  short* wkT = (short*)(wsw);
  short* wqT = (short*)(wsw + ((size_t)512 << 10));
  short* wvT = (short*)(wsw + ((size_t)1024 << 10));
  short* woB = (short*)(wsw + ((size_t)1536 << 10));
  short* w1B = (short*)(wsw + ((size_t)2048 << 10));
  short* w2B = (short*)(wsw + ((size_t)3072 << 10));
  short* AT  = (short*)(wsw + ((size_t)5120 << 10));
  short* MB  = (short*)(wsw + ((size_t)5632 << 10));
  float* t2  = (float*)(wsw + ((size_t)6144 << 10));
  float* c0v = (float*)(wsw + ((size_t)6144 << 10) + 2048);
  float* bnsum   = (float*)(wsw + ((size_t)6144 << 10) + 4096);
  float* bnsumsq = (float*)(wsw + ((size_t)6144 << 10) + 6144);

  short* Gb = (short*)d_out;   // G bf16 16384x1024 = 32 MiB, lives in d_out until LN overwrites

  hipMemsetAsync(bnsum, 0, 4096, stream);

  transpose_in_k<<<dim3(8, 8, 32), 256, 0, stream>>>(residual, Xb);
  tcast3_k<<<dim3(8, 8, 3), 256, 0, stream>>>(wk, wq, wv, wkT, wqT, wvT);
  cast3_k<<<640, 256, 0, stream>>>(wo, w1, w2, woB, w1B, w2B);
  t2c0_k<<<dim3(2, 2), 256, 0, stream>>>(bq, wk, wo, bv, bo, t2, c0v);

  // z=0: A_T[t][d]=sum_e wk[e][t]*wq[e][d]; z=1: M[e][t]=sum_d wo[e][d]*wv[d][t]
  gemm_k<4><<<dim3(4, 4, 2), 256, 0, stream>>>(wkT, wqT, woB, wvT, 512, 512, 512,
      nullptr, nullptr, AT, MB, nullptr, nullptr, nullptr);

  // Y = X @ A_T^T + t2
  gemm_k<0><<<dim3(128, 4), 256, 0, stream>>>(Xb, AT, nullptr, nullptr, NROW, 512, 512,
      t2, nullptr, YZ, nullptr, nullptr, nullptr, nullptr);
  // scores/softmax/z (in place Y->Z)
  attn_k<<<1024, 256, 0, stream>>>(Xb, YZ);
  // H = Z @ M^T + c0 + X (bf16); BN stats in fp32 pre-round
  gemm_k<1><<<dim3(128, 4), 256, 0, stream>>>(YZ, MB, nullptr, nullptr, NROW, 512, 512,
      c0v, Xb, Hb, nullptr, nullptr, bnsum, bnsumsq);
  // hn (BN finalize fused)
  make_hn_k<<<4096, 256, 0, stream>>>(Hb, bnsum, bnsumsq, bn_w, bn_b, HNb);
  // G = gelu(HN @ W1^T + b1)
  gemm_k<2><<<dim3(128, 8), 256, 0, stream>>>(HNb, w1B, nullptr, nullptr, NROW, 1024, 512,
      b1, nullptr, Gb, nullptr, nullptr, nullptr, nullptr);
  // y = G @ W2^T + b2 + HN
  gemm_k<3><<<dim3(128, 4), 256, 0, stream>>>(Gb, w2B, nullptr, nullptr, NROW, 512, 1024,
      b2, nullptr, YZ, nullptr, HNb, nullptr, nullptr);
  // LayerNorm + transposed output
  ln_transpose_k<<<256, 256, 0, stream>>>(YZ, ln_w, ln_b, (float*)d_out);
}